// Round 4
// baseline (345.645 us; speedup 1.0000x reference)
//
#include <hip/hip_runtime.h>
#include <hip/hip_bf16.h>
#include <stdint.h>

typedef __bf16 bf16x8 __attribute__((ext_vector_type(8)));
typedef __bf16 bf16x4 __attribute__((ext_vector_type(4)));
typedef float  f32x4  __attribute__((ext_vector_type(4)));
typedef float  f32x2  __attribute__((ext_vector_type(2)));

#define MFMA16(a,b,c) __builtin_amdgcn_mfma_f32_16x16x32_bf16((a),(b),(c),0,0,0)

static constexpr int H_   = 256;
static constexpr int KEV  = 10;
static constexpr int NTOK = 32 * 4096;
static constexpr int NCHUNK = 48;          // 3 layers x 16 chunks of 16 output feats

// Pade(5,5) tanh: x*(945+105t+t^2)/(945+420t+15t^2), |err|<7e-4 with clamp. 1 transcendental.
__device__ __forceinline__ float ptanh(float x){
    float t = x * x;
    float n = fmaf(t, t + 105.0f, 945.0f);
    float d = fmaf(t, fmaf(t, 15.0f, 420.0f), 945.0f);
    float r = x * n * __builtin_amdgcn_rcpf(d);
    return fminf(1.0f, fmaxf(-1.0f, r));
}

// async global->LDS 16B/lane: HW dest = wave-uniform base + lane*16 (m104/m108)
__device__ __forceinline__ void cp16(void* lds, const void* g){
    auto l = reinterpret_cast<__attribute__((address_space(3))) uint32_t*>(
                 (uint32_t)reinterpret_cast<uintptr_t>(lds));
    auto s = reinterpret_cast<const __attribute__((address_space(1))) uint32_t*>(
                 reinterpret_cast<uintptr_t>(g));
    __builtin_amdgcn_global_load_lds(s, l, 16, 0, 0);
}

__device__ __forceinline__ bf16x8 cvtFrag(const float* p){
    f32x4 a = *(const f32x4*)p;
    f32x4 b = *(const f32x4*)(p + 4);
    bf16x8 r;
    #pragma unroll
    for (int j = 0; j < 4; ++j){ r[j] = (__bf16)a[j]; r[4 + j] = (__bf16)b[j]; }
    return r;
}

// ---- prep 1: v1[j] = sum_k w2[j][256+k]*w1[k]; c1[j] = sum_k w2[j][256+k]*b1[k] + b2[j]
__global__ void prep_vc(const float* __restrict__ w1, const float* __restrict__ b1,
                        const float* __restrict__ w2, const float* __restrict__ b2,
                        float* __restrict__ vc){
    int j = blockIdx.x * 4 + (threadIdx.x >> 6);
    int l = threadIdx.x & 63;
    const float* row = w2 + (size_t)j * (2 * H_) + H_;
    float v = 0.f, cc = 0.f;
    #pragma unroll
    for (int i = 0; i < 4; ++i){
        int k = l + 64 * i;
        float w = row[k];
        v  += w * w1[k];
        cc += w * b1[k];
    }
    #pragma unroll
    for (int off = 32; off; off >>= 1){
        v  += __shfl_down(v,  off, 64);
        cc += __shfl_down(cc, off, 64);
    }
    if (l == 0){ vc[j] = v; vc[H_ + j] = cc + b2[j]; }
}

// ---- prep 2: pack weights to bf16 in MFMA fragment order.
// chunk b (layer b>>4, n0 = b&15): slot = (s*4+q)*16+c holds W[n0*16+c][32s+8q .. +8]
__global__ void prep_pack(const float* __restrict__ w2, const float* __restrict__ wA,
                          const float* __restrict__ wB, __hip_bfloat16* __restrict__ pk){
    int b  = blockIdx.x;
    int L  = b >> 4, n0 = b & 15;
    const float* W = (L == 0) ? w2 : ((L == 1) ? wA : wB);
    int K = (L == 0) ? 2 * H_ : H_;       // layer1 uses first 256 cols of w2
    __hip_bfloat16* dst = pk + (size_t)b * 4096;
    int t = threadIdx.x;
    #pragma unroll
    for (int u = 0; u < 2; ++u){
        int slot = t * 2 + u;
        int s = slot >> 6, q = (slot >> 4) & 3, c = slot & 15;
        const float* src = W + (size_t)(n0 * 16 + c) * K + 32 * s + 8 * q;
        #pragma unroll
        for (int j = 0; j < 8; ++j) dst[slot * 8 + j] = __float2bfloat16(src[j]);
    }
}

__global__ __launch_bounds__(256, 2) void chfn_kernel(
    const float* __restrict__ hs, const float* __restrict__ td,
    const __hip_bfloat16* __restrict__ wpk,
    const float* __restrict__ bA, const float* __restrict__ bB,
    const float* __restrict__ w3, const float* __restrict__ b3,
    const float* __restrict__ vc,
    float* __restrict__ out)
{
    __shared__ __hip_bfloat16 sA[4 * 16 * H_];     // 32 KB activations  [token][feat] swizzled
    __shared__ __hip_bfloat16 sD[4 * 16 * H_];     // 32 KB tangents
    __shared__ __hip_bfloat16 wls[2][4096];        // 2 x 8 KB weight-chunk ring (80 KB total)

    const int tid  = threadIdx.x;
    const int wave = tid >> 6;
    const int lane = tid & 63;
    const int q    = lane >> 4;
    const int c    = lane & 15;       // token index within tile (col of transposed D)
    const int tokenBase = blockIdx.x * 64 + wave * 16;
    const int wrow = wave * 16;

    // h fragments (fp32 stream, one-time). Same bits serve as B-operand (col=token).
    const float* hrow = hs + (size_t)(tokenBase + c) * H_ + 8 * q;
    f32x4 h0[8], h1[8];
    #pragma unroll
    for (int s = 0; s < 8; ++s){
        h0[s] = *(const f32x4*)(hrow + 32 * s);
        h1[s] = *(const f32x4*)(hrow + 32 * s + 4);
    }

    // stage chunk 0: wave w copies KBs [2w, 2w+2)
    #pragma unroll
    for (int j = 0; j < 2; ++j){
        int i = wave * 2 + j;
        cp16((char*)&wls[0][0] + i * 1024, (const char*)wpk + i * 1024 + lane * 16);
    }

    float myTd = td[tokenBase + c];   // token = c in transposed layout: no shuffle needed

    bf16x8 aF[8], aB[8];
    #pragma unroll
    for (int s = 0; s < 8; ++s){
        bf16x8 rr;
        #pragma unroll
        for (int j = 0; j < 4; ++j){ rr[j] = (__bf16)h0[s][j]; rr[4 + j] = (__bf16)h1[s][j]; }
        aF[s] = rr;
    }

    __syncthreads();   // chunk 0 staged

    int g = 0;
    // ---- layer 1: D[feat][token]; x = D + td*v1[f] + c1[f]; tanh; tangent = (1-th^2)*v1[f]
    #pragma unroll 1
    for (int n0 = 0; n0 < 16; ++n0, ++g){
        const __hip_bfloat16* cur = wls[g & 1];
        {
            const char* src = (const char*)(wpk + (size_t)(g + 1) * 4096);
            #pragma unroll
            for (int j = 0; j < 2; ++j){
                int i = wave * 2 + j;
                cp16((char*)&wls[(g + 1) & 1][0] + i * 1024, src + i * 1024 + lane * 16);
            }
        }
        f32x4 fa = {0.f,0.f,0.f,0.f}, fb = {0.f,0.f,0.f,0.f};
        #pragma unroll
        for (int s = 0; s < 4; ++s){
            bf16x8 bv0 = *(const bf16x8*)(cur + ((s * 4 + q) * 16 + c) * 8);
            bf16x8 bv1 = *(const bf16x8*)(cur + (((s + 4) * 4 + q) * 16 + c) * 8);
            fa = MFMA16(bv0, aF[s],     fa);   // swapped operands: D[feat row][token col]
            fb = MFMA16(bv1, aF[s + 4], fb);
        }
        int nb = n0 * 16 + 4 * q;                 // this lane's 4 consecutive feats
        f32x4 v4 = *(const f32x4*)(vc + nb);
        f32x4 c4 = *(const f32x4*)(vc + H_ + nb);
        bf16x4 pa, pd;
        #pragma unroll
        for (int r = 0; r < 4; ++r){
            float x  = (fa[r] + fb[r]) + fmaf(myTd, v4[r], c4[r]);
            float th = ptanh(x);
            float dd = fmaf(-th, th, 1.0f) * v4[r];
            pa[r] = (__bf16)th; pd[r] = (__bf16)dd;
        }
        int ch  = 2 * n0 + (q >> 1);
        int off = (wrow + c) * H_ + (((ch + c) & 31) << 3) + ((q & 1) << 2);
        *(bf16x4*)((void*)(sA + off)) = pa;
        *(bf16x4*)((void*)(sD + off)) = pd;
        __syncthreads();
    }

    // ---- layers 2 & 3
    const float* bias2[2] = {bA, bB};
    #pragma unroll 1
    for (int L = 0; L < 2; ++L){
        const float* bias = bias2[L];
        const __hip_bfloat16* arow = sA + (wrow + c) * H_;
        const __hip_bfloat16* drow = sD + (wrow + c) * H_;
        #pragma unroll
        for (int s = 0; s < 8; ++s){
            int chn = (((4 * s + q) + c) & 31) << 3;
            aF[s] = *(const bf16x8*)(arow + chn);
            aB[s] = *(const bf16x8*)(drow + chn);
        }
        #pragma unroll 1
        for (int n0 = 0; n0 < 16; ++n0, ++g){
            const __hip_bfloat16* cur = wls[g & 1];
            if (g + 1 < NCHUNK){
                const char* src = (const char*)(wpk + (size_t)(g + 1) * 4096);
                #pragma unroll
                for (int j = 0; j < 2; ++j){
                    int i = wave * 2 + j;
                    cp16((char*)&wls[(g + 1) & 1][0] + i * 1024, src + i * 1024 + lane * 16);
                }
            }
            f32x4 fa = {0.f,0.f,0.f,0.f}, fb = {0.f,0.f,0.f,0.f};
            f32x4 ga = {0.f,0.f,0.f,0.f}, gb = {0.f,0.f,0.f,0.f};
            #pragma unroll
            for (int s = 0; s < 4; ++s){
                bf16x8 bv0 = *(const bf16x8*)(cur + ((s * 4 + q) * 16 + c) * 8);
                bf16x8 bv1 = *(const bf16x8*)(cur + (((s + 4) * 4 + q) * 16 + c) * 8);
                fa = MFMA16(bv0, aF[s],     fa);
                ga = MFMA16(bv0, aB[s],     ga);
                fb = MFMA16(bv1, aF[s + 4], fb);
                gb = MFMA16(bv1, aB[s + 4], gb);
            }
            int nb = n0 * 16 + 4 * q;
            f32x4 b4 = *(const f32x4*)(bias + nb);
            bf16x4 pa, pd;
            #pragma unroll
            for (int r = 0; r < 4; ++r){
                float th = ptanh((fa[r] + fb[r]) + b4[r]);
                float dd = fmaf(-th, th, 1.0f) * (ga[r] + gb[r]);
                pa[r] = (__bf16)th; pd[r] = (__bf16)dd;
            }
            int ch  = 2 * n0 + (q >> 1);
            int off = (wrow + c) * H_ + (((ch + c) & 31) << 3) + ((q & 1) << 2);
            *(bf16x4*)((void*)(sA + off)) = pa;
            *(bf16x4*)((void*)(sD + off)) = pd;
            __syncthreads();
        }
    }

    // ---- head (K=10): rows = feats 4q+r (valid <10), cols = tokens c (all 16 valid)
    {
        const __hip_bfloat16* arow = sA + (wrow + c) * H_;
        const __hip_bfloat16* drow = sD + (wrow + c) * H_;
        #pragma unroll
        for (int s = 0; s < 8; ++s){
            int chn = (((4 * s + q) + c) & 31) << 3;
            aF[s] = *(const bf16x8*)(arow + chn);
            aB[s] = *(const bf16x8*)(drow + chn);
        }
        int crow = (c < KEV) ? c : 0;   // A-operand row clamp; rows>=10 never stored
        const float* wp0 = w3 + (size_t)crow * H_ + 8 * q;
        f32x4 fa = {0.f,0.f,0.f,0.f}, fb = {0.f,0.f,0.f,0.f};
        f32x4 ga = {0.f,0.f,0.f,0.f}, gb = {0.f,0.f,0.f,0.f};
        #pragma unroll
        for (int s = 0; s < 4; ++s){
            bf16x8 bv0 = cvtFrag(wp0 + 32 * s);
            bf16x8 bv1 = cvtFrag(wp0 + 32 * (s + 4));
            fa = MFMA16(bv0, aF[s],     fa);
            ga = MFMA16(bv0, aB[s],     ga);
            fb = MFMA16(bv1, aF[s + 4], fb);
            gb = MFMA16(bv1, aB[s + 4], gb);
        }
        int fbase = 4 * q;
        size_t token = tokenBase + c;
        float sp[4], dv[4];
        #pragma unroll
        for (int r = 0; r < 4; ++r){
            int fi  = fbase + r;
            float bn = b3[(fi < KEV) ? fi : (KEV - 1)];
            float z  = (fa[r] + fb[r]) + bn;
            float a  = fabsf(z);
            float e  = __builtin_amdgcn_exp2f(-1.4426950408889634f * a);     // exp(-|z|)
            sp[r] = fmaxf(z, 0.f) + 0.69314718055994531f * __builtin_amdgcn_logf(1.0f + e);
            float sg = __builtin_amdgcn_rcpf(1.0f + e);
            sg = (z >= 0.f) ? sg : 1.0f - sg;                                 // sigmoid(z)
            dv[r] = sg * (ga[r] + gb[r]) * (1.0f / 131072.0f);                // /(B*S)
        }
        float* o0 = out + token * KEV + fbase;
        float* o1 = out + (size_t)NTOK * KEV + token * KEV + fbase;
        if (q < 2){
            *(f32x2*)o0       = (f32x2){sp[0], sp[1]};
            *(f32x2*)(o0 + 2) = (f32x2){sp[2], sp[3]};
            *(f32x2*)o1       = (f32x2){dv[0], dv[1]};
            *(f32x2*)(o1 + 2) = (f32x2){dv[2], dv[3]};
        } else if (q == 2){
            *(f32x2*)o0 = (f32x2){sp[0], sp[1]};
            *(f32x2*)o1 = (f32x2){dv[0], dv[1]};
        }
    }
}

extern "C" void kernel_launch(void* const* d_in, const int* in_sizes, int n_in,
                              void* d_out, int out_size, void* d_ws, size_t ws_size,
                              hipStream_t stream){
    const float* hs = (const float*)d_in[0];
    const float* td = (const float*)d_in[1];
    const float* w1 = (const float*)d_in[2];
    const float* b1 = (const float*)d_in[3];
    const float* w2 = (const float*)d_in[4];
    const float* b2 = (const float*)d_in[5];
    const float* wA = (const float*)d_in[6];
    const float* bA = (const float*)d_in[7];
    const float* wB = (const float*)d_in[8];
    const float* bB = (const float*)d_in[9];
    const float* w3 = (const float*)d_in[10];
    const float* b3 = (const float*)d_in[11];

    float*          vc  = (float*)d_ws;                              // 512 fp32
    __hip_bfloat16* wpk = (__hip_bfloat16*)((char*)d_ws + 4096);     // 48*8KB packed weights
    float*          outp = (float*)d_out;

    prep_vc  <<<64, 256, 0, stream>>>(w1, b1, w2, b2, vc);
    prep_pack<<<48, 256, 0, stream>>>(w2, wA, wB, wpk);
    chfn_kernel<<<NTOK / 64, 256, 0, stream>>>(hs, td, wpk, bA, bB, w3, b3, vc, outp);
}